// Round 1
// baseline (252.980 us; speedup 1.0000x reference)
//
#include <hip/hip_runtime.h>

// Problem: fasterRCNN box decode + per-class argmax region pick.
// Inputs (float32): boxes (N,4), box_deltas (N,28), scores (N,7), im_info (3)
// Outputs (float32, concatenated): pred_boxes (N*28), region_g (5), region_l (5)
//
// Stage 1 (fused): one thread per (row,class) pair p = i*7+c, grid-stride
//   UNROLLED x4 with all 12 loads batched per iteration. Rationale: previous
//   version compiled to 12 VGPRs -> loads serialized behind s_waitcnt ->
//   latency-bound at 2.4 TB/s (VALUBusy 12%, HBM 38% of achievable). Batching
//   4 independent (deltas,boxes,scores) triples gives ~4x memory-level
//   parallelism per wave while staying <=64 VGPRs (full 8 waves/SIMD).
//   pred stores are non-temporal: output is write-once (finalize reads only
//   8 floats), keeps the 156 MB of inputs resident in L2/L3.
// Per-class argmax (classes 1..6) with exact first-index tie-break:
//   key = (monotone(score) << 32) | (0xFFFFFFFF - i); LDS atomicMax per block
//   with 4B hi-word pre-check. sbest initialized to the THRESH key so
//   below-threshold lanes never touch the atomic (kills the iter-0 stampede).
// Stage 2 (tiny): reduce per-block winners, decode idx/score, gather box from
//   pred output, write the two 5-float regions.

#define THRESH_F 0.05f
#define NCLS 7
#define BLOCKS 2048
#define TPB 256

typedef float f4 __attribute__((ext_vector_type(4)));

__device__ __forceinline__ unsigned map_float(unsigned bits) {
    // monotone map float bits -> unsigned (order-preserving for all finite floats)
    return (bits & 0x80000000u) ? ~bits : (bits | 0x80000000u);
}

__device__ __forceinline__ f4 decode_one(f4 d, f4 b, float maxX, float maxY) {
    const float w  = b.z - b.x + 1.0f;
    const float h  = b.w - b.y + 1.0f;
    const float cx = b.x + 0.5f * w;
    const float cy = b.y + 0.5f * h;

    const float pcx = (d.x * 0.1f) * w + cx;
    const float pcy = (d.y * 0.1f) * h + cy;
    const float pw  = __expf(d.z * 0.2f) * w * 0.5f;
    const float ph  = __expf(d.w * 0.2f) * h * 0.5f;

    f4 o;
    o.x = fminf(fmaxf(pcx - pw, 0.0f), maxX);
    o.y = fminf(fmaxf(pcy - ph, 0.0f), maxY);
    o.z = fminf(fmaxf(pcx + pw, 0.0f), maxX);
    o.w = fminf(fmaxf(pcy + ph, 0.0f), maxY);
    return o;
}

__device__ __forceinline__ void pick_one(unsigned i, unsigned c, float s,
                                         unsigned long long* sbest) {
    if (c == 0u) return;
    const float m = (s > THRESH_F) ? s : -1.0f;
    const unsigned mapped = map_float(__float_as_uint(m));
    const int slot = (int)c - 1;
    // 4B hi-word pre-check (atomic wrt tearing) to skip most LDS atomics
    const unsigned curhi = ((volatile const unsigned*)sbest)[slot * 2 + 1];
    if (mapped >= curhi) {
        const unsigned long long key =
            ((unsigned long long)mapped << 32) |
            (unsigned long long)(0xFFFFFFFFu - i);
        atomicMax(&sbest[slot], key);
    }
}

__global__ __launch_bounds__(TPB, 8) void decode_pick_kernel(
    const f4*   __restrict__ boxes,
    const f4*   __restrict__ deltas,
    const float* __restrict__ scores,
    const float* __restrict__ im_info,
    f4*         __restrict__ pred,
    unsigned long long* __restrict__ blockbest,
    int NP)
{
    __shared__ unsigned long long sbest[6];
    const int tid = threadIdx.x;
    if (tid < 6)
        sbest[tid] = ((unsigned long long)map_float(__float_as_uint(THRESH_F)) << 32);
    __syncthreads();

    const float maxX = im_info[1] - 1.0f;   // W-1 = 999
    const float maxY = im_info[0] - 1.0f;   // H-1 = 599

    const int stride = gridDim.x * blockDim.x;
    int p = blockIdx.x * blockDim.x + tid;

    // ---- main loop: unroll x4, batch all loads first (MLP) ----
    for (; p + 3 * stride < NP; p += 4 * stride) {
        const int p0 = p;
        const int p1 = p + stride;
        const int p2 = p + 2 * stride;
        const int p3 = p + 3 * stride;

        const unsigned i0 = (unsigned)p0 / 7u;
        const unsigned i1 = (unsigned)p1 / 7u;
        const unsigned i2 = (unsigned)p2 / 7u;
        const unsigned i3 = (unsigned)p3 / 7u;

        // 12 independent loads issued back-to-back
        const f4 d0 = deltas[p0];
        const f4 d1 = deltas[p1];
        const f4 d2 = deltas[p2];
        const f4 d3 = deltas[p3];
        const f4 b0 = boxes[i0];
        const f4 b1 = boxes[i1];
        const f4 b2 = boxes[i2];
        const f4 b3 = boxes[i3];
        const float s0 = scores[p0];
        const float s1 = scores[p1];
        const float s2 = scores[p2];
        const float s3 = scores[p3];

        __builtin_nontemporal_store(decode_one(d0, b0, maxX, maxY), &pred[p0]);
        __builtin_nontemporal_store(decode_one(d1, b1, maxX, maxY), &pred[p1]);
        __builtin_nontemporal_store(decode_one(d2, b2, maxX, maxY), &pred[p2]);
        __builtin_nontemporal_store(decode_one(d3, b3, maxX, maxY), &pred[p3]);

        pick_one(i0, (unsigned)p0 - i0 * 7u, s0, sbest);
        pick_one(i1, (unsigned)p1 - i1 * 7u, s1, sbest);
        pick_one(i2, (unsigned)p2 - i2 * 7u, s2, sbest);
        pick_one(i3, (unsigned)p3 - i3 * 7u, s3, sbest);
    }

    // ---- tail ----
    for (; p < NP; p += stride) {
        const unsigned i = (unsigned)p / 7u;
        const f4 d = deltas[p];
        const f4 b = boxes[i];
        const float s = scores[p];
        __builtin_nontemporal_store(decode_one(d, b, maxX, maxY), &pred[p]);
        pick_one(i, (unsigned)p - i * 7u, s, sbest);
    }

    __syncthreads();
    if (tid < 6)
        blockbest[(size_t)blockIdx.x * 6 + tid] = sbest[tid];
}

__global__ __launch_bounds__(TPB) void finalize_kernel(
    const unsigned long long* __restrict__ blockbest,
    int nblocks,
    const float* __restrict__ pred,
    float*       __restrict__ regions)   // d_out + N*28, 10 floats
{
    __shared__ unsigned long long red[TPB];
    __shared__ unsigned long long fin[6];
    const int tid = threadIdx.x;

    for (int slot = 0; slot < 6; ++slot) {
        unsigned long long k = 0ULL;
        for (int j = tid; j < nblocks; j += TPB) {
            unsigned long long v = blockbest[(size_t)j * 6 + slot];
            k = (v > k) ? v : k;
        }
        red[tid] = k;
        __syncthreads();
        for (int off = TPB / 2; off > 0; off >>= 1) {
            if (tid < off) {
                unsigned long long v = red[tid + off];
                if (v > red[tid]) red[tid] = v;
            }
            __syncthreads();
        }
        if (tid == 0) fin[slot] = red[0];
        __syncthreads();
    }

    if (tid == 0) {
        for (int g = 0; g < 2; ++g) {
            float scores_[3];
            unsigned idx_[3];
            float bestScore = -1e30f;
            int bestJ = 0;
            for (int j = 0; j < 3; ++j) {
                const unsigned long long key = fin[g * 3 + j];
                const unsigned hi = (unsigned)(key >> 32);
                const unsigned bits = (hi & 0x80000000u) ? (hi & 0x7FFFFFFFu) : ~hi;
                const float sc = __uint_as_float(bits);
                const unsigned idx = 0xFFFFFFFFu - (unsigned)(key & 0xFFFFFFFFu);
                scores_[j] = sc;
                idx_[j] = idx;
                if (sc > bestScore) { bestScore = sc; bestJ = j; }  // strict > : first-max tie-break
            }
            const int c = g * 3 + bestJ + 1;
            const unsigned i = idx_[bestJ];
            const float* pb = pred + (size_t)i * 28 + (size_t)c * 4;
            float* r = regions + g * 5;
            r[0] = pb[0];
            r[1] = pb[1];
            r[2] = pb[2];
            r[3] = pb[3];
            r[4] = scores_[bestJ];
        }
    }
}

extern "C" void kernel_launch(void* const* d_in, const int* in_sizes, int n_in,
                              void* d_out, int out_size, void* d_ws, size_t ws_size,
                              hipStream_t stream) {
    const float* boxes   = (const float*)d_in[0];
    const float* deltas  = (const float*)d_in[1];
    const float* scores  = (const float*)d_in[2];
    const float* im_info = (const float*)d_in[3];

    const int N  = in_sizes[0] / 4;      // 1,000,000
    const int NP = N * NCLS;             // 7,000,000 (row,class) pairs

    float* out = (float*)d_out;
    float* regions = out + (size_t)N * 4 * NCLS;   // after pred_boxes

    unsigned long long* blockbest = (unsigned long long*)d_ws;  // BLOCKS*6*8 = 96 KB

    decode_pick_kernel<<<BLOCKS, TPB, 0, stream>>>(
        (const f4*)boxes, (const f4*)deltas, scores, im_info,
        (f4*)out, blockbest, NP);

    finalize_kernel<<<1, TPB, 0, stream>>>(blockbest, BLOCKS, out, regions);
}

// Round 2
// 249.261 us; speedup vs baseline: 1.0149x; 1.0149x over previous
//
#include <hip/hip_runtime.h>

// Problem: fasterRCNN box decode + per-class argmax region pick.
// Inputs (float32): boxes (N,4), box_deltas (N,28), scores (N,7), im_info (3)
// Outputs (float32, concatenated): pred_boxes (N*28), region_g (5), region_l (5)
//
// Stage 1 (fused): one thread per (row,class) pair p = i*7+c.
//   MEMCPY-SHAPED ACCESS PATTERN: each block owns a CONTIGUOUS chunk of
//   TPB*4 = 1024 pairs (16 KB of deltas / 16 KB of pred) per grid-stride
//   step; threads unroll x4 at +TPB offsets within the chunk. Rationale
//   (round-1 post-mortem): unrolling with 8 MB-apart streams created 8192
//   concurrent DRAM streams and REGRESSED (87 us vs 80); reps where L3
//   fully absorbed reads ran at identical speed -> not HBM-read-bound,
//   limited by outstanding-request capacity / DRAM page locality. The
//   6.3 TB/s memcpy reference uses exactly this block-contiguous unroll
//   with one stream per block (2048 streams total).
//   pred stores are non-temporal: output is write-once (finalize reads only
//   8 floats); keeps the inputs resident in L2/L3 across reps.
// Per-class argmax (classes 1..6) with exact first-index tie-break:
//   key = (monotone(score) << 32) | (0xFFFFFFFF - i); LDS atomicMax per block
//   with 4B hi-word pre-check. sbest initialized to the THRESH key so
//   below-threshold lanes never touch the atomic.
// Stage 2 (tiny): reduce per-block winners, decode idx/score, gather box from
//   pred output, write the two 5-float regions.

#define THRESH_F 0.05f
#define NCLS 7
#define BLOCKS 2048
#define TPB 256
#define UNROLL 4
#define CHUNK (TPB * UNROLL)   // 1024 pairs = 16 KB of float4

typedef float f4 __attribute__((ext_vector_type(4)));

__device__ __forceinline__ unsigned map_float(unsigned bits) {
    // monotone map float bits -> unsigned (order-preserving for all finite floats)
    return (bits & 0x80000000u) ? ~bits : (bits | 0x80000000u);
}

__device__ __forceinline__ f4 decode_one(f4 d, f4 b, float maxX, float maxY) {
    const float w  = b.z - b.x + 1.0f;
    const float h  = b.w - b.y + 1.0f;
    const float cx = b.x + 0.5f * w;
    const float cy = b.y + 0.5f * h;

    const float pcx = (d.x * 0.1f) * w + cx;
    const float pcy = (d.y * 0.1f) * h + cy;
    const float pw  = __expf(d.z * 0.2f) * w * 0.5f;
    const float ph  = __expf(d.w * 0.2f) * h * 0.5f;

    f4 o;
    o.x = fminf(fmaxf(pcx - pw, 0.0f), maxX);
    o.y = fminf(fmaxf(pcy - ph, 0.0f), maxY);
    o.z = fminf(fmaxf(pcx + pw, 0.0f), maxX);
    o.w = fminf(fmaxf(pcy + ph, 0.0f), maxY);
    return o;
}

__device__ __forceinline__ void pick_one(unsigned i, unsigned c, float s,
                                         unsigned long long* sbest) {
    if (c == 0u) return;
    const float m = (s > THRESH_F) ? s : -1.0f;
    const unsigned mapped = map_float(__float_as_uint(m));
    const int slot = (int)c - 1;
    // 4B hi-word pre-check (atomic wrt tearing) to skip most LDS atomics
    const unsigned curhi = ((volatile const unsigned*)sbest)[slot * 2 + 1];
    if (mapped >= curhi) {
        const unsigned long long key =
            ((unsigned long long)mapped << 32) |
            (unsigned long long)(0xFFFFFFFFu - i);
        atomicMax(&sbest[slot], key);
    }
}

__global__ __launch_bounds__(TPB, 8) void decode_pick_kernel(
    const f4*   __restrict__ boxes,
    const f4*   __restrict__ deltas,
    const float* __restrict__ scores,
    const float* __restrict__ im_info,
    f4*         __restrict__ pred,
    unsigned long long* __restrict__ blockbest,
    int NP)
{
    __shared__ unsigned long long sbest[6];
    const int tid = threadIdx.x;
    if (tid < 6)
        sbest[tid] = ((unsigned long long)map_float(__float_as_uint(THRESH_F)) << 32);
    __syncthreads();

    const float maxX = im_info[1] - 1.0f;   // W-1 = 999
    const float maxY = im_info[0] - 1.0f;   // H-1 = 599

    // ---- main loop: block-contiguous chunks of CHUNK pairs, unroll x4 ----
    const int nchunks = NP / CHUNK;          // full chunks
    for (int ch = blockIdx.x; ch < nchunks; ch += gridDim.x) {
        const int base = ch * CHUNK + tid;
        const int p0 = base;
        const int p1 = base + TPB;
        const int p2 = base + 2 * TPB;
        const int p3 = base + 3 * TPB;

        const unsigned i0 = (unsigned)p0 / 7u;
        const unsigned i1 = (unsigned)p1 / 7u;
        const unsigned i2 = (unsigned)p2 / 7u;
        const unsigned i3 = (unsigned)p3 / 7u;

        // 12 independent loads, all within one 16 KB chunk (one DRAM stream/block)
        const f4 d0 = deltas[p0];
        const f4 d1 = deltas[p1];
        const f4 d2 = deltas[p2];
        const f4 d3 = deltas[p3];
        const f4 b0 = boxes[i0];
        const f4 b1 = boxes[i1];
        const f4 b2 = boxes[i2];
        const f4 b3 = boxes[i3];
        const float s0 = scores[p0];
        const float s1 = scores[p1];
        const float s2 = scores[p2];
        const float s3 = scores[p3];

        __builtin_nontemporal_store(decode_one(d0, b0, maxX, maxY), &pred[p0]);
        __builtin_nontemporal_store(decode_one(d1, b1, maxX, maxY), &pred[p1]);
        __builtin_nontemporal_store(decode_one(d2, b2, maxX, maxY), &pred[p2]);
        __builtin_nontemporal_store(decode_one(d3, b3, maxX, maxY), &pred[p3]);

        pick_one(i0, (unsigned)p0 - i0 * 7u, s0, sbest);
        pick_one(i1, (unsigned)p1 - i1 * 7u, s1, sbest);
        pick_one(i2, (unsigned)p2 - i2 * 7u, s2, sbest);
        pick_one(i3, (unsigned)p3 - i3 * 7u, s3, sbest);
    }

    // ---- tail: remaining NP - nchunks*CHUNK pairs (< CHUNK) ----
    for (int p = nchunks * CHUNK + blockIdx.x * TPB + tid; p < NP;
         p += gridDim.x * TPB) {
        const unsigned i = (unsigned)p / 7u;
        const f4 d = deltas[p];
        const f4 b = boxes[i];
        const float s = scores[p];
        __builtin_nontemporal_store(decode_one(d, b, maxX, maxY), &pred[p]);
        pick_one(i, (unsigned)p - i * 7u, s, sbest);
    }

    __syncthreads();
    if (tid < 6)
        blockbest[(size_t)blockIdx.x * 6 + tid] = sbest[tid];
}

__global__ __launch_bounds__(TPB) void finalize_kernel(
    const unsigned long long* __restrict__ blockbest,
    int nblocks,
    const float* __restrict__ pred,
    float*       __restrict__ regions)   // d_out + N*28, 10 floats
{
    __shared__ unsigned long long red[TPB];
    __shared__ unsigned long long fin[6];
    const int tid = threadIdx.x;

    for (int slot = 0; slot < 6; ++slot) {
        unsigned long long k = 0ULL;
        for (int j = tid; j < nblocks; j += TPB) {
            unsigned long long v = blockbest[(size_t)j * 6 + slot];
            k = (v > k) ? v : k;
        }
        red[tid] = k;
        __syncthreads();
        for (int off = TPB / 2; off > 0; off >>= 1) {
            if (tid < off) {
                unsigned long long v = red[tid + off];
                if (v > red[tid]) red[tid] = v;
            }
            __syncthreads();
        }
        if (tid == 0) fin[slot] = red[0];
        __syncthreads();
    }

    if (tid == 0) {
        for (int g = 0; g < 2; ++g) {
            float scores_[3];
            unsigned idx_[3];
            float bestScore = -1e30f;
            int bestJ = 0;
            for (int j = 0; j < 3; ++j) {
                const unsigned long long key = fin[g * 3 + j];
                const unsigned hi = (unsigned)(key >> 32);
                const unsigned bits = (hi & 0x80000000u) ? (hi & 0x7FFFFFFFu) : ~hi;
                const float sc = __uint_as_float(bits);
                const unsigned idx = 0xFFFFFFFFu - (unsigned)(key & 0xFFFFFFFFu);
                scores_[j] = sc;
                idx_[j] = idx;
                if (sc > bestScore) { bestScore = sc; bestJ = j; }  // strict > : first-max tie-break
            }
            const int c = g * 3 + bestJ + 1;
            const unsigned i = idx_[bestJ];
            const float* pb = pred + (size_t)i * 28 + (size_t)c * 4;
            float* r = regions + g * 5;
            r[0] = pb[0];
            r[1] = pb[1];
            r[2] = pb[2];
            r[3] = pb[3];
            r[4] = scores_[bestJ];
        }
    }
}

extern "C" void kernel_launch(void* const* d_in, const int* in_sizes, int n_in,
                              void* d_out, int out_size, void* d_ws, size_t ws_size,
                              hipStream_t stream) {
    const float* boxes   = (const float*)d_in[0];
    const float* deltas  = (const float*)d_in[1];
    const float* scores  = (const float*)d_in[2];
    const float* im_info = (const float*)d_in[3];

    const int N  = in_sizes[0] / 4;      // 1,000,000
    const int NP = N * NCLS;             // 7,000,000 (row,class) pairs

    float* out = (float*)d_out;
    float* regions = out + (size_t)N * 4 * NCLS;   // after pred_boxes

    unsigned long long* blockbest = (unsigned long long*)d_ws;  // BLOCKS*6*8 = 96 KB

    decode_pick_kernel<<<BLOCKS, TPB, 0, stream>>>(
        (const f4*)boxes, (const f4*)deltas, scores, im_info,
        (f4*)out, blockbest, NP);

    finalize_kernel<<<1, TPB, 0, stream>>>(blockbest, BLOCKS, out, regions);
}